// Round 7
// baseline (239.275 us; speedup 1.0000x reference)
//
#include <hip/hip_runtime.h>
#include <hip/hip_fp16.h>
#include <stdint.h>

#define FREQS 10
#define DDIM 120   // 6 coords * 2 (sin,cos) * 10 freqs

typedef _Float16 half2v __attribute__((ext_vector_type(2)));

static __device__ __forceinline__ uint32_t pk(float lo, float hi) {
    half2v h = {(_Float16)lo, (_Float16)hi};
    return *(uint32_t*)&h;
}

static __device__ __forceinline__ float fdot2f(uint32_t a, uint32_t b, float c) {
#if __has_builtin(__builtin_amdgcn_fdot2)
    return __builtin_amdgcn_fdot2(*(half2v*)&a, *(half2v*)&b, c, false);
#else
    half2v av = *(half2v*)&a, bv = *(half2v*)&b;
    return fmaf((float)av.x, (float)bv.x, fmaf((float)av.y, (float)bv.y, c));
#endif
}

static __device__ __forceinline__ void atomAddF(float* p, float v) {
#if defined(__HIP_DEVICE_COMPILE__) && defined(__AMDGCN__)
    unsafeAtomicAdd(p, v);   // native global_atomic_add_f32
#else
    atomicAdd(p, v);
#endif
}

// K0: W fp32 [3C][120] -> fp16 same layout, 4 elems/thread
__global__ __launch_bounds__(256) void convert_w_f16(
    const float4* __restrict__ W4, uint2* __restrict__ Wh4, int n4)
{
    int i = blockIdx.x * blockDim.x + threadIdx.x;
    if (i < n4) {
        float4 v = W4[i];
        Wh4[i] = make_uint2(pk(v.x, v.y), pk(v.z, v.w));
    }
}

// K1: zero out[] (poisoned 0xAA; atomics need 0) and hist[]
__global__ __launch_bounds__(256) void zero_misc(
    float* __restrict__ out, int n_out, uint32_t* __restrict__ hist, int C)
{
    int i = blockIdx.x * blockDim.x + threadIdx.x;
    if (i < n_out) out[i] = 0.f;
    if (i < C)     hist[i] = 0u;
}

// K2: per-cluster histogram of the 3N (row,k) entries. Requires C <= 256.
__global__ __launch_bounds__(256) void count_k(
    const int* __restrict__ ids, uint32_t* __restrict__ hist, int N)
{
    __shared__ uint32_t lh[256];
    int t = threadIdx.x;
    lh[t] = 0u;
    __syncthreads();
    int n = blockIdx.x * 256 + t;
    if (n < N) {
        atomicAdd(&lh[ids[3 * n + 0]], 1u);
        atomicAdd(&lh[ids[3 * n + 1]], 1u);
        atomicAdd(&lh[ids[3 * n + 2]], 1u);
    }
    __syncthreads();
    uint32_t v = lh[t];
    if (v) atomicAdd(&hist[t], v);   // t>=C has v==0 (ids < C)
}

// K3: exclusive scan of hist -> cursor (single 256-thread block; C <= 256)
__global__ __launch_bounds__(256) void scan_k(
    const uint32_t* __restrict__ hist, uint32_t* __restrict__ cursor, int C)
{
    __shared__ uint32_t s[256];
    int t = threadIdx.x;
    uint32_t v = (t < C) ? hist[t] : 0u;
    s[t] = v;
    __syncthreads();
    for (int off = 1; off < 256; off <<= 1) {
        uint32_t add = (t >= off) ? s[t - off] : 0u;
        __syncthreads();
        s[t] += add;
        __syncthreads();
    }
    if (t < C) cursor[t] = s[t] - v;   // exclusive prefix
}

// K4: scatter entries sorted by cluster. LDS-aggregated to cut global
// atomic contention: one global atomicAdd per (block,cluster).
// entry = n | (k<<20) | (c<<22)   (N < 2^20, k < 4, C <= 256)
__global__ __launch_bounds__(256) void scatter_k(
    const int* __restrict__ ids, uint32_t* __restrict__ cursor,
    uint32_t* __restrict__ entries, int N)
{
    __shared__ uint32_t lh[256];
    __shared__ uint32_t gbase[256];
    int t = threadIdx.x;
    lh[t] = 0u;
    __syncthreads();
    int n = blockIdx.x * 256 + t;
    bool v = (n < N);
    uint32_t c_[3], lr[3];
    if (v) {
#pragma unroll
        for (int k = 0; k < 3; ++k) {
            c_[k] = (uint32_t)ids[3 * n + k];
            lr[k] = atomicAdd(&lh[c_[k]], 1u);
        }
    }
    __syncthreads();
    uint32_t cnt = lh[t];
    if (cnt) gbase[t] = atomicAdd(&cursor[t], cnt);
    __syncthreads();
    if (v) {
#pragma unroll
        for (int k = 0; k < 3; ++k)
            entries[gbase[c_[k]] + lr[k]] =
                (uint32_t)n | ((uint32_t)k << 20) | (c_[k] << 22);
    }
}

// K5: main — one thread per (row,k) entry, entries sorted by cluster so a
// wave's W loads are (near-)uniform -> HW broadcast, ~1 line per instr.
__global__ __launch_bounds__(256) void main_k(
    const float* __restrict__ X,
    const uint16_t* __restrict__ Wh,     // fp16 [3C][120]
    const float* __restrict__ weights,   // [3, N]
    const uint32_t* __restrict__ entries,
    float* __restrict__ out,             // [N, 3], pre-zeroed
    int N, int M)
{
    int g = blockIdx.x * 256 + threadIdx.x;
    if (g >= M) return;
    uint32_t e = entries[g];
    int n = (int)(e & 0xFFFFFu);
    int k = (int)((e >> 20) & 3u);
    int c = (int)(e >> 22);

    const float2* xp = (const float2*)(X + (size_t)n * 6);
    float2 a0 = xp[0], a1 = xp[1], a2 = xp[2];
    float x[6] = {a0.x, a0.y, a1.x, a1.y, a2.x, a2.y};
    if (x[0] == -1.0f && x[1] == -1.0f && x[2] == -1.0f) return;  // masked row stays 0

    float wk = weights[(size_t)k * N + n];

    // enc (validated in round 4): 12 transcendentals + double-angle recurrence.
    // E dword i covers elements (2i, 2i+1); element d = f*12+t, t<6: sin(x_t*2^f),
    // t>=6: cos(x_{t-6}*2^f).
    float s_[6], c_[6];
#pragma unroll
    for (int j = 0; j < 6; ++j) { s_[j] = __sinf(x[j]); c_[j] = __cosf(x[j]); }

    uint32_t E[60];
#pragma unroll
    for (int f = 0; f < FREQS; ++f) {
        E[f * 6 + 0] = pk(s_[0], s_[1]);
        E[f * 6 + 1] = pk(s_[2], s_[3]);
        E[f * 6 + 2] = pk(s_[4], s_[5]);
        E[f * 6 + 3] = pk(c_[0], c_[1]);
        E[f * 6 + 4] = pk(c_[2], c_[3]);
        E[f * 6 + 5] = pk(c_[4], c_[5]);
        if (f < FREQS - 1) {
#pragma unroll
            for (int j = 0; j < 6; ++j) {
                float ts = s_[j] + s_[j];
                float sn = ts * c_[j];
                float cn = fmaf(-ts, s_[j], 1.0f);
                s_[j] = sn; c_[j] = cn;
            }
        }
    }

    // 3 output rows x 120 fp16 = 45 x uint4, 16B aligned (720*c % 16 == 0).
    const uint4* wb = (const uint4*)(Wh + (size_t)c * (3 * DDIM));
    float acc[3] = {0.f, 0.f, 0.f};
#pragma unroll
    for (int ch = 0; ch < 45; ++ch) {
        const int r  = ch / 15;          // static after unroll
        const int cc = ch % 15;
        uint4 wv = wb[ch];
        acc[r] = fdot2f(E[cc * 4 + 0], wv.x, acc[r]);
        acc[r] = fdot2f(E[cc * 4 + 1], wv.y, acc[r]);
        acc[r] = fdot2f(E[cc * 4 + 2], wv.z, acc[r]);
        acc[r] = fdot2f(E[cc * 4 + 3], wv.w, acc[r]);
    }

    float* op = out + (size_t)n * 3;
    atomAddF(op + 0, wk * acc[0]);
    atomAddF(op + 1, wk * acc[1]);
    atomAddF(op + 2, wk * acc[2]);
}

// fp32 fallback (ws too small or C>256): known-correct per-thread path.
__global__ __launch_bounds__(256) void clnet_kernel_f32(
    const float* __restrict__ X, const float* __restrict__ W,
    const float* __restrict__ weights, const int* __restrict__ ids,
    float* __restrict__ out, int N)
{
    int n = blockIdx.x * blockDim.x + threadIdx.x;
    if (n >= N) return;
    const float2* xp = (const float2*)(X + (size_t)n * 6);
    float2 a0 = xp[0], a1 = xp[1], a2 = xp[2];
    float x[6] = {a0.x, a0.y, a1.x, a1.y, a2.x, a2.y};
    bool mask = (x[0] == -1.0f) && (x[1] == -1.0f) && (x[2] == -1.0f);

    float E[DDIM];
#pragma unroll
    for (int f = 0; f < FREQS; ++f) {
        float scale = (float)(1 << f);
#pragma unroll
        for (int j = 0; j < 6; ++j) {
            float v = x[j] * scale;
            E[f * 12 + j] = __sinf(v); E[f * 12 + 6 + j] = __cosf(v);
        }
    }
    float rgb[3] = {0.f, 0.f, 0.f};
#pragma unroll
    for (int k = 0; k < 3; ++k) {
        int cc = ids[(size_t)n * 3 + k];
        float wkk = weights[(size_t)k * N + n];
        const float4* wp = (const float4*)(W + (size_t)cc * (3 * DDIM));
        float acc[3] = {0.f, 0.f, 0.f};
#pragma unroll
        for (int ch = 0; ch < 90; ++ch) {
            float4 v = wp[ch];
            const int r = ch / 30, dbase = (ch % 30) * 4;
            acc[r] = fmaf(E[dbase + 0], v.x, acc[r]);
            acc[r] = fmaf(E[dbase + 1], v.y, acc[r]);
            acc[r] = fmaf(E[dbase + 2], v.z, acc[r]);
            acc[r] = fmaf(E[dbase + 3], v.w, acc[r]);
        }
        rgb[0] = fmaf(wkk, acc[0], rgb[0]);
        rgb[1] = fmaf(wkk, acc[1], rgb[1]);
        rgb[2] = fmaf(wkk, acc[2], rgb[2]);
    }
    if (mask) { rgb[0] = 0.f; rgb[1] = 0.f; rgb[2] = 0.f; }
    out[(size_t)n * 3 + 0] = rgb[0];
    out[(size_t)n * 3 + 1] = rgb[1];
    out[(size_t)n * 3 + 2] = rgb[2];
}

extern "C" void kernel_launch(void* const* d_in, const int* in_sizes, int n_in,
                              void* d_out, int out_size, void* d_ws, size_t ws_size,
                              hipStream_t stream)
{
    const float* X       = (const float*)d_in[0];
    const float* W       = (const float*)d_in[1];
    const float* weights = (const float*)d_in[2];
    const int*   ids     = (const int*)d_in[3];
    float*       out     = (float*)d_out;

    const int N = in_sizes[0] / 6;             // 262144
    const int C = in_sizes[1] / (3 * DDIM);    // 256 clusters
    const int M = 3 * N;                       // entries

    // d_ws layout (16B-aligned sections): Wh fp16 | hist u32[C] | cursor u32[C] | entries u32[M]
    const size_t wh_bytes   = (size_t)C * 3 * DDIM * 2;     // 720*C
    const size_t hist_off   = wh_bytes;                     // 720C % 16 == 0
    const size_t cursor_off = hist_off + (size_t)C * 4;
    const size_t entry_off  = cursor_off + (size_t)C * 4;
    const size_t need       = entry_off + (size_t)M * 4;

    const int blk = 256;

    if (ws_size >= need && C <= 256 && N < (1 << 20)) {
        char* ws = (char*)d_ws;
        uint16_t* Wh      = (uint16_t*)(ws);
        uint32_t* hist    = (uint32_t*)(ws + hist_off);
        uint32_t* cursor  = (uint32_t*)(ws + cursor_off);
        uint32_t* entries = (uint32_t*)(ws + entry_off);

        int n4 = (C * 3 * DDIM) / 4;
        convert_w_f16<<<(n4 + blk - 1) / blk, blk, 0, stream>>>(
            (const float4*)W, (uint2*)Wh, n4);
        zero_misc<<<(M + blk - 1) / blk, blk, 0, stream>>>(out, M, hist, C);
        count_k<<<(N + blk - 1) / blk, blk, 0, stream>>>(ids, hist, N);
        scan_k<<<1, blk, 0, stream>>>(hist, cursor, C);
        scatter_k<<<(N + blk - 1) / blk, blk, 0, stream>>>(ids, cursor, entries, N);
        main_k<<<(M + blk - 1) / blk, blk, 0, stream>>>(
            X, Wh, weights, entries, out, N, M);
    } else {
        clnet_kernel_f32<<<(N + blk - 1) / blk, blk, 0, stream>>>(
            X, W, weights, ids, out, N);
    }
}

// Round 9
// 90.215 us; speedup vs baseline: 2.6523x; 2.6523x over previous
//
#include <hip/hip_runtime.h>
#include <hip/hip_fp16.h>
#include <stdint.h>

#define FREQS 10
#define DDIM 120   // 6 coords * 2 (sin,cos) * 10 freqs

typedef _Float16 half2v __attribute__((ext_vector_type(2)));

static __device__ __forceinline__ uint32_t pk(float lo, float hi) {
    half2v h = {(_Float16)lo, (_Float16)hi};
    return *(uint32_t*)&h;
}

static __device__ __forceinline__ float fdot2f(uint32_t a, uint32_t b, float c) {
#if __has_builtin(__builtin_amdgcn_fdot2)
    return __builtin_amdgcn_fdot2(*(half2v*)&a, *(half2v*)&b, c, false);
#else
    half2v av = *(half2v*)&a, bv = *(half2v*)&b;
    return fmaf((float)av.x, (float)bv.x, fmaf((float)av.y, (float)bv.y, c));
#endif
}

// --- Convert W (fp32 [3C][120]) to fp16 chunked layout in d_ws ---
// cluster c, chunk ch in [0,CK): wrow = ch/RS, cc = ch%RS.
// cc<15: 8 fp16 of W[3c+wrow][cc*8 .. +7]. cc==15 (padded layout only): zeros.
template <int CK, int RS>
__global__ __launch_bounds__(256) void convert_w(
    const float* __restrict__ W, uint4* __restrict__ Wp, int nclusters)
{
    int idx = blockIdx.x * blockDim.x + threadIdx.x;
    if (idx >= nclusters * CK) return;
    int c = idx / CK, ch = idx % CK;
    int wrow = ch / RS, cc = ch % RS;
    uint4 d = make_uint4(0u, 0u, 0u, 0u);
    if (cc < 15) {
        const float* src = W + ((size_t)(3 * c + wrow) * DDIM + cc * 8);
        float4 a = *(const float4*)(src);
        float4 b = *(const float4*)(src + 4);
        d.x = pk(a.x, a.y); d.y = pk(a.z, a.w);
        d.z = pk(b.x, b.y); d.w = pk(b.z, b.w);
    }
    Wp[idx] = d;
}

// --- Quad-cooperative kernel: 4 lanes per row ---
// Lane l loads W chunks 4i+l of each row (quad covers one aligned 64B line/instr).
// Matching E chunk is 4i+l -> after LDS exchange each lane keeps E chunks
// {l, l+4, l+8, l+12} = 4 x uint4 = 16 VGPR. Row's E chunk 15 is ZEROED in LDS
// (padded W chunk 15 is zero, and 0*garbage could be NaN -- round-5 bug).
template <int CK, int RS>
__global__ __launch_bounds__(256, 4) void clnet_quad(
    const float* __restrict__ X,
    const uint4* __restrict__ Wp,       // [C][CK] 16B chunks, fp16
    const float* __restrict__ weights,  // [3, N]
    const int*   __restrict__ ids,      // [N, 3]
    float*       __restrict__ out,      // [N, 3]
    int N)
{
    __shared__ uint32_t elds[64 * 68];  // 64 rows x 272 B (17 chunks)

    const int tid = threadIdx.x;
    const int q = tid >> 2, l = tid & 3;
    const int n = blockIdx.x * 64 + q;
    const bool valid = (n < N);

    float x[6];
    bool mask = false;
    int cid[3] = {0, 0, 0};
    float wk[3] = {0.f, 0.f, 0.f};
    const unsigned eb = q * 68;  // dword base of this row's E region

    if (valid) {
        const float2* xp = (const float2*)(X + (size_t)n * 6);
        float2 a0 = xp[0], a1 = xp[1], a2 = xp[2];
        x[0] = a0.x; x[1] = a0.y; x[2] = a1.x; x[3] = a1.y; x[4] = a2.x; x[5] = a2.y;
        mask = (x[0] == -1.0f) && (x[1] == -1.0f) && (x[2] == -1.0f);
#pragma unroll
        for (int k = 0; k < 3; ++k) {
            cid[k] = ids[(size_t)n * 3 + k];
            wk[k]  = weights[(size_t)k * N + n];
        }

        // Cooperative enc: lane l computes freqs l, l+4, l+8 (f<10).
        // E element d = f*12 + t: t<6 -> sin(x_t*2^f), t>=6 -> cos(x_{t-6}*2^f).
#pragma unroll
        for (int fi = 0; fi < 3; ++fi) {
            int f = l + 4 * fi;
            if (f < FREQS) {
                float scale = (float)(1 << f);
                float s_[6], c_[6];
#pragma unroll
                for (int j = 0; j < 6; ++j) {
                    float v = x[j] * scale;
                    s_[j] = __sinf(v); c_[j] = __cosf(v);
                }
                unsigned o = eb + f * 6;
                *(uint2*)&elds[o + 0] = make_uint2(pk(s_[0], s_[1]), pk(s_[2], s_[3]));
                *(uint2*)&elds[o + 2] = make_uint2(pk(s_[4], s_[5]), pk(c_[0], c_[1]));
                *(uint2*)&elds[o + 4] = make_uint2(pk(c_[2], c_[3]), pk(c_[4], c_[5]));
            }
        }
        if (l == 3) {  // zero the pad chunk (dwords 60..63) - NaN guard
            *(uint4*)&elds[eb + 60] = make_uint4(0u, 0u, 0u, 0u);
        }
    }

    __syncthreads();   // all 256 threads reach this (no earlier returns)

    if (!valid) return;

    uint4 E[4];
#pragma unroll
    for (int j = 0; j < 4; ++j)
        E[j] = *(const uint4*)&elds[eb + (4 * j + l) * 4];  // chunk 4j+l (15 = zeros)

    float rgb[3] = {0.f, 0.f, 0.f};

#pragma unroll
    for (int k = 0; k < 3; ++k) {
        const uint4* base = Wp + (size_t)cid[k] * CK;
        float acc[3] = {0.f, 0.f, 0.f};
#pragma unroll
        for (int r = 0; r < 3; ++r) {
#pragma unroll
            for (int i = 0; i < 4; ++i) {
                // Unpadded layout (RS==15): chunk 15 doesn't exist -> skip i==3,l==3.
                if (RS == 16 || i < 3 || l < 3) {
                    uint4 wv = base[r * RS + 4 * i + l];
                    acc[r] = fdot2f(E[i].x, wv.x, acc[r]);
                    acc[r] = fdot2f(E[i].y, wv.y, acc[r]);
                    acc[r] = fdot2f(E[i].z, wv.z, acc[r]);
                    acc[r] = fdot2f(E[i].w, wv.w, acc[r]);
                }
            }
        }
        rgb[0] = fmaf(wk[k], acc[0], rgb[0]);
        rgb[1] = fmaf(wk[k], acc[1], rgb[1]);
        rgb[2] = fmaf(wk[k], acc[2], rgb[2]);
    }

    // Quad reduce (xor 1, xor 2 stay within the quad).
#pragma unroll
    for (int r = 0; r < 3; ++r) {
        rgb[r] += __shfl_xor(rgb[r], 1);
        rgb[r] += __shfl_xor(rgb[r], 2);
    }

    if (l < 3) {
        float v = (l == 0) ? rgb[0] : (l == 1) ? rgb[1] : rgb[2];
        if (mask) v = 0.f;
        out[(size_t)n * 3 + l] = v;
    }
}

// --- fp32 fallback (ws too small): known-correct per-thread path ---
__global__ __launch_bounds__(256) void clnet_kernel_f32(
    const float* __restrict__ X, const float* __restrict__ W,
    const float* __restrict__ weights, const int* __restrict__ ids,
    float* __restrict__ out, int N)
{
    int n = blockIdx.x * blockDim.x + threadIdx.x;
    if (n >= N) return;
    const float2* xp = (const float2*)(X + (size_t)n * 6);
    float2 a0 = xp[0], a1 = xp[1], a2 = xp[2];
    float x[6] = {a0.x, a0.y, a1.x, a1.y, a2.x, a2.y};
    bool mask = (x[0] == -1.0f) && (x[1] == -1.0f) && (x[2] == -1.0f);

    float E[DDIM];
#pragma unroll
    for (int f = 0; f < FREQS; ++f) {
        float scale = (float)(1 << f);
#pragma unroll
        for (int j = 0; j < 6; ++j) {
            float v = x[j] * scale;
            E[f * 12 + j] = __sinf(v); E[f * 12 + 6 + j] = __cosf(v);
        }
    }
    float rgb[3] = {0.f, 0.f, 0.f};
#pragma unroll
    for (int k = 0; k < 3; ++k) {
        int cc = ids[(size_t)n * 3 + k];
        float wkk = weights[(size_t)k * N + n];
        const float4* wp = (const float4*)(W + (size_t)cc * (3 * DDIM));
        float acc[3] = {0.f, 0.f, 0.f};
#pragma unroll
        for (int ch = 0; ch < 90; ++ch) {
            float4 v = wp[ch];
            const int r = ch / 30, dbase = (ch % 30) * 4;
            acc[r] = fmaf(E[dbase + 0], v.x, acc[r]);
            acc[r] = fmaf(E[dbase + 1], v.y, acc[r]);
            acc[r] = fmaf(E[dbase + 2], v.z, acc[r]);
            acc[r] = fmaf(E[dbase + 3], v.w, acc[r]);
        }
        rgb[0] = fmaf(wkk, acc[0], rgb[0]);
        rgb[1] = fmaf(wkk, acc[1], rgb[1]);
        rgb[2] = fmaf(wkk, acc[2], rgb[2]);
    }
    if (mask) { rgb[0] = 0.f; rgb[1] = 0.f; rgb[2] = 0.f; }
    out[(size_t)n * 3 + 0] = rgb[0];
    out[(size_t)n * 3 + 1] = rgb[1];
    out[(size_t)n * 3 + 2] = rgb[2];
}

extern "C" void kernel_launch(void* const* d_in, const int* in_sizes, int n_in,
                              void* d_out, int out_size, void* d_ws, size_t ws_size,
                              hipStream_t stream)
{
    const float* X       = (const float*)d_in[0];
    const float* W       = (const float*)d_in[1];
    const float* weights = (const float*)d_in[2];
    const int*   ids     = (const int*)d_in[3];
    float*       out     = (float*)d_out;

    const int N = in_sizes[0] / 6;             // 262144
    const int C = in_sizes[1] / (3 * DDIM);    // 256 clusters

    const size_t need48 = (size_t)C * 48 * 16; // 196608 B (padded rows, preferred)
    const size_t need45 = (size_t)C * 45 * 16; // 184320 B (unpadded fallback)

    const int blk = 256;
    const int gridMain = (N + 63) / 64;        // 4 lanes per row

    if (ws_size >= need48) {
        uint4* Wp = (uint4*)d_ws;
        int nchunk = C * 48;
        convert_w<48, 16><<<(nchunk + blk - 1) / blk, blk, 0, stream>>>(W, Wp, C);
        clnet_quad<48, 16><<<gridMain, blk, 0, stream>>>(X, Wp, weights, ids, out, N);
    } else if (ws_size >= need45) {
        uint4* Wp = (uint4*)d_ws;
        int nchunk = C * 45;
        convert_w<45, 15><<<(nchunk + blk - 1) / blk, blk, 0, stream>>>(W, Wp, C);
        clnet_quad<45, 15><<<gridMain, blk, 0, stream>>>(X, Wp, weights, ids, out, N);
    } else {
        clnet_kernel_f32<<<(N + blk - 1) / blk, blk, 0, stream>>>(
            X, W, weights, ids, out, N);
    }
}